// Round 1
// baseline (94.199 us; speedup 1.0000x reference)
//
#include <hip/hip_runtime.h>
#include <math.h>

// Fidelity of 4-qubit embedding circuits: out = |<psi(f2)|psi(f1)>|^2,
// psi(f) = [diag(P(f)) * (1/4) * WHT16]^3 |0>, where P folds all RZ + ZZ
// phases of one layer (they commute past the H gates on other wires).
// One thread per sample; the 16-amp complex state lives in VGPRs.

#define PI_F 3.14159265358979323846f

__device__ __forceinline__ void fast_sincos(float x, float& s, float& c) {
    const float INV2PI = 0.15915494309189535f;
    const float TWOPI  = 6.283185307179586f;
    float k = rintf(x * INV2PI);
    float r = fmaf(-k, TWOPI, x);   // r in ~[-pi, pi]
    s = __sinf(r);
    c = __cosf(r);
}

// Phase table for one circuit, prescaled by 1/4 (the H⊗4 normalization).
// Wire w maps to bit (3-w): wire0 -> mask 8, wire1 -> 4, wire2 -> 2, wire3 -> 1.
// Phi(s) = -sum_j f_j*sigma_j + sum_{(a,b)} (pi-f_a)(pi-f_b)*sigma_a*sigma_b
// (since sigma_{a XOR b} = -sigma_a*sigma_b).
__device__ __forceinline__ void phase_table(const float f[4], float cs[16], float sn[16]) {
    float g0 = PI_F - f[0], g1 = PI_F - f[1], g2 = PI_F - f[2], g3 = PI_F - f[3];
    float p01 = g0 * g1, p12 = g1 * g2, p23 = g2 * g3, p30 = g3 * g0;
#pragma unroll
    for (int s = 0; s < 16; ++s) {
        const float s0 = (s & 8) ? 1.f : -1.f;
        const float s1 = (s & 4) ? 1.f : -1.f;
        const float s2 = (s & 2) ? 1.f : -1.f;
        const float s3 = (s & 1) ? 1.f : -1.f;
        float phi = -(f[0] * s0 + f[1] * s1 + f[2] * s2 + f[3] * s3)
                  + p01 * (s0 * s1) + p12 * (s1 * s2)
                  + p23 * (s2 * s3) + p30 * (s3 * s0);
        float sv, cv;
        fast_sincos(phi, sv, cv);
        sn[s] = 0.25f * sv;
        cs[s] = 0.25f * cv;
    }
}

// psi = [diag(0.25*P) * WHT16]^3 |0>.  Layer 1 on |0> is just the table.
__device__ __forceinline__ void run_circuit(const float cs[16], const float sn[16],
                                            float re[16], float im[16]) {
#pragma unroll
    for (int s = 0; s < 16; ++s) { re[s] = cs[s]; im[s] = sn[s]; }
#pragma unroll
    for (int layer = 1; layer < 3; ++layer) {
        // unscaled 16-pt Walsh-Hadamard on re and im (H on all 4 wires)
#pragma unroll
        for (int m = 1; m < 16; m <<= 1) {
#pragma unroll
            for (int s = 0; s < 16; ++s) {
                if (!(s & m)) {
                    float ar = re[s], br = re[s | m];
                    re[s] = ar + br; re[s | m] = ar - br;
                    float ai = im[s], bi = im[s | m];
                    im[s] = ai + bi; im[s | m] = ai - bi;
                }
            }
        }
        // diagonal phases (prescaled by 1/4)
#pragma unroll
        for (int s = 0; s < 16; ++s) {
            float r = re[s] * cs[s] - im[s] * sn[s];
            float i = re[s] * sn[s] + im[s] * cs[s];
            re[s] = r; im[s] = i;
        }
    }
}

// MLP 4->8->8->4 on two inputs simultaneously (weight loads shared).
__device__ __forceinline__ void mlp_dual(
    const float xa[4], const float xb[4],
    const float* __restrict__ W1, const float* __restrict__ b1,
    const float* __restrict__ W2, const float* __restrict__ b2,
    const float* __restrict__ W3, const float* __restrict__ b3,
    float fa[4], float fb[4]) {
    float h1a[8], h1b[8];
#pragma unroll
    for (int k = 0; k < 8; ++k) {
        float aa = b1[k], ab = aa;
#pragma unroll
        for (int j = 0; j < 4; ++j) {
            float w = W1[j * 8 + k];
            aa = fmaf(xa[j], w, aa);
            ab = fmaf(xb[j], w, ab);
        }
        h1a[k] = fmaxf(aa, 0.f);
        h1b[k] = fmaxf(ab, 0.f);
    }
    float h2a[8], h2b[8];
#pragma unroll
    for (int k = 0; k < 8; ++k) {
        float aa = b2[k], ab = aa;
#pragma unroll
        for (int j = 0; j < 8; ++j) {
            float w = W2[j * 8 + k];
            aa = fmaf(h1a[j], w, aa);
            ab = fmaf(h1b[j], w, ab);
        }
        h2a[k] = fmaxf(aa, 0.f);
        h2b[k] = fmaxf(ab, 0.f);
    }
#pragma unroll
    for (int k = 0; k < 4; ++k) {
        float aa = b3[k], ab = aa;
#pragma unroll
        for (int j = 0; j < 8; ++j) {
            float w = W3[j * 4 + k];
            aa = fmaf(h2a[j], w, aa);
            ab = fmaf(h2b[j], w, ab);
        }
        fa[k] = aa;
        fb[k] = ab;
    }
}

__global__ __launch_bounds__(256) void fidelity_kernel(
    const float* __restrict__ x1, const float* __restrict__ x2,
    const float* __restrict__ W1, const float* __restrict__ b1,
    const float* __restrict__ W2, const float* __restrict__ b2,
    const float* __restrict__ W3, const float* __restrict__ b3,
    float* __restrict__ out, int n) {
    int tid = blockIdx.x * 256 + threadIdx.x;
    if (tid >= n) return;

    float4 a4 = ((const float4*)x1)[tid];
    float4 b4 = ((const float4*)x2)[tid];
    float xa[4] = {a4.x, a4.y, a4.z, a4.w};
    float xb[4] = {b4.x, b4.y, b4.z, b4.w};

    float fa[4], fb[4];
    mlp_dual(xa, xb, W1, b1, W2, b2, W3, b3, fa, fb);

    float cs[16], sn[16];
    float re1[16], im1[16];
    phase_table(fa, cs, sn);
    run_circuit(cs, sn, re1, im1);

    float re2[16], im2[16];
    phase_table(fb, cs, sn);
    run_circuit(cs, sn, re2, im2);

    // <psi2|psi1> = sum conj(psi2)*psi1
    float dr = 0.f, di = 0.f;
#pragma unroll
    for (int s = 0; s < 16; ++s) {
        dr = fmaf(re2[s], re1[s], dr);
        dr = fmaf(im2[s], im1[s], dr);
        di = fmaf(re2[s], im1[s], di);
        di = fmaf(-im2[s], re1[s], di);
    }
    out[tid] = dr * dr + di * di;
}

extern "C" void kernel_launch(void* const* d_in, const int* in_sizes, int n_in,
                              void* d_out, int out_size, void* d_ws, size_t ws_size,
                              hipStream_t stream) {
    const float* x1 = (const float*)d_in[0];
    const float* x2 = (const float*)d_in[1];
    const float* W1 = (const float*)d_in[2];
    const float* b1 = (const float*)d_in[3];
    const float* W2 = (const float*)d_in[4];
    const float* b2 = (const float*)d_in[5];
    const float* W3 = (const float*)d_in[6];
    const float* b3 = (const float*)d_in[7];
    float* out = (float*)d_out;

    int n = out_size;  // B samples
    int block = 256;
    int grid = (n + block - 1) / block;
    fidelity_kernel<<<grid, block, 0, stream>>>(x1, x2, W1, b1, W2, b2, W3, b3, out, n);
}